// Round 5
// baseline (817.272 us; speedup 1.0000x reference)
//
#include <hip/hip_runtime.h>

#define MIN_NORM 1e-15f
#define EPSV 1e-5f
#define MAXN (1.0f - EPSV)
#define NN 8192
#define DD 128

typedef unsigned short u16;
typedef __bf16 bf16x8 __attribute__((ext_vector_type(8)));
typedef float f32x4 __attribute__((ext_vector_type(4)));

__device__ __forceinline__ float wave_sum(float v) {
#pragma unroll
  for (int off = 32; off > 0; off >>= 1) v += __shfl_xor(v, off, 64);
  return v;
}

__device__ __forceinline__ float artanh_f(float x) {
  x = fminf(fmaxf(x, -1.0f + EPSV), 1.0f - EPSV);
  return 0.5f * (log1pf(x) - log1pf(-x));
}

// manual fp32 -> bf16 (RNE) and back
__device__ __forceinline__ u16 f2bf(float f) {
  unsigned u = __float_as_uint(f);
  unsigned r = (u + 0x7fffu + ((u >> 16) & 1u)) >> 16;
  return (u16)r;
}
__device__ __forceinline__ float bf2f(u16 b) { return __uint_as_float(((unsigned)b) << 16); }

// async global->LDS DMA, 16 B per lane. LDS dest = wave-uniform base + lane*16.
__device__ __forceinline__ void gload16(const u16* g, u16* l) {
  __builtin_amdgcn_global_load_lds((const __attribute__((address_space(1))) void*)(g),
                                   (__attribute__((address_space(3))) void*)(l), 16, 0, 0);
}

// ---------------------------------------------------------------------------
// GEMM: C[M][128] = A[M][K] * Bt[128][K]^T (both bf16; Bt n-major, k-fast).
// Split-K via blockIdx.y -> partial buffer Cp + y*M*128.
// BM=64, BN=128, BK=64; 256 threads = 4 waves (2x2), wave tile 32x64.
// Staging: __builtin_amdgcn_global_load_lds (async DMA, no VGPR roundtrip;
// cannot be scheduler-sunk, unlike rounds 2-4's reg-staging which the
// compiler defeated). Double-buffered LDS, one barrier per K-tile:
//   STAGE(buf0); loop { barrier (drains vmcnt->buf[cur] ready, guards reuse);
//                       STAGE(buf[cur^1], t+1); compute(buf[cur]); }
// HBM latency of tile t+1 hides under tile t's ds_read+MFMA.
// LDS is LINEAR (global_load_lds requirement) with both-sides XOR swizzle:
// 16-B chunk c of row r lives at physical chunk c^(r&7). Staging pre-swizzles
// the GLOBAL source chunk; reads apply the same XOR. This spreads the
// 16-rows-same-column ds_read_b128 pattern across all 8 bank-quads (optimal).
// ---------------------------------------------------------------------------
__global__ __launch_bounds__(256) void gemm_bt(const u16* __restrict__ A,
                                               const u16* __restrict__ Bt,
                                               float* __restrict__ Cp,
                                               int M, int K, int KC) {
  __shared__ __align__(16) u16 Ash[2 * 64 * 64];    // 16 KB (2 bufs)
  __shared__ __align__(16) u16 Bsh[2 * 128 * 64];   // 32 KB (2 bufs)

  const int tid = threadIdx.x;
  const int lane = tid & 63;
  const int w = tid >> 6;
  const int wm = w >> 1, wn = w & 1;
  const int lrow = lane & 15;
  const int lq = lane >> 4;
  const int m0 = blockIdx.x * 64;
  const int kk0 = blockIdx.y * KC;

  const int srow = lane >> 3;   // staging: sub-row within 8-row group
  const int spc = lane & 7;     // staging: physical chunk this lane fills

  const u16* Ap = A + (size_t)m0 * K;

  f32x4 acc[2][4];
#pragma unroll
  for (int a = 0; a < 2; a++)
#pragma unroll
    for (int b = 0; b < 4; b++)
#pragma unroll
      for (int r = 0; r < 4; r++) acc[a][b][r] = 0.0f;

  // STAGE: issue 6 async 16-B DMAs (2 for A-tile, 4 for B-tile) into buffer bf.
  // Lane covers physical (row, spc); global source chunk = spc ^ (row&7).
#define STAGE(bf, kk)                                                          \
  do {                                                                         \
    _Pragma("unroll") for (int ii = 0; ii < 2; ii++) {                         \
      int rw = ((ii * 4 + w) << 3) + srow;                                     \
      gload16(Ap + (size_t)rw * K + (kk) + ((spc ^ (rw & 7)) << 3),            \
              &Ash[(bf) * 4096 + ((ii * 4 + w) << 9)]);                        \
    }                                                                          \
    _Pragma("unroll") for (int ii = 0; ii < 4; ii++) {                         \
      int rw = ((ii * 4 + w) << 3) + srow;                                     \
      gload16(Bt + (size_t)rw * K + (kk) + ((spc ^ (rw & 7)) << 3),            \
              &Bsh[(bf) * 8192 + ((ii * 4 + w) << 9)]);                        \
    }                                                                          \
  } while (0)

  const int nt = KC >> 6;
  STAGE(0, kk0);  // prologue

  for (int t = 0; t < nt; t++) {
    const int cur = t & 1;
    __syncthreads();  // compiler emits vmcnt(0): buf[cur] complete; also all
                      // waves done reading buf[cur^1] -> safe to overwrite
    if (t + 1 < nt) STAGE(cur ^ 1, kk0 + (t + 1) * 64);

    const int abase = cur * 4096, bbase = cur * 8192;
#pragma unroll
    for (int ks = 0; ks < 2; ks++) {
      const int lc = ks * 4 + lq;  // logical 16-B chunk within row
      bf16x8 af[2], bfr[4];
#pragma unroll
      for (int ti = 0; ti < 2; ti++) {
        int r = wm * 32 + ti * 16 + lrow;
        af[ti] = *(const bf16x8*)&Ash[abase + r * 64 + ((lc ^ (r & 7)) << 3)];
      }
#pragma unroll
      for (int tj = 0; tj < 4; tj++) {
        int n = wn * 64 + tj * 16 + lrow;
        bfr[tj] = *(const bf16x8*)&Bsh[bbase + n * 64 + ((lc ^ (n & 7)) << 3)];
      }
#pragma unroll
      for (int ti = 0; ti < 2; ti++)
#pragma unroll
        for (int tj = 0; tj < 4; tj++)
          acc[ti][tj] = __builtin_amdgcn_mfma_f32_16x16x32_bf16(af[ti], bfr[tj], acc[ti][tj], 0, 0, 0);
    }
  }
#undef STAGE

  float* C = Cp + (size_t)blockIdx.y * M * 128;
#pragma unroll
  for (int ti = 0; ti < 2; ti++)
#pragma unroll
    for (int tj = 0; tj < 4; tj++)
#pragma unroll
      for (int r = 0; r < 4; r++) {
        int row = m0 + wm * 32 + ti * 16 + lq * 4 + r;
        int col = wn * 64 + tj * 16 + lrow;
        C[(size_t)row * 128 + col] = acc[ti][tj][r];
      }
}

// streaming fp32 -> bf16 conversion of adj (pure BW, no latency pathology)
__global__ __launch_bounds__(256) void cvt_adj(const float* __restrict__ src,
                                               u16* __restrict__ dst) {
  const size_t stride = (size_t)gridDim.x * 256 * 8;
  for (size_t base = ((size_t)blockIdx.x * 256 + threadIdx.x) * 8;
       base < (size_t)NN * NN; base += stride) {
    float4 a = *(const float4*)(src + base);
    float4 b = *(const float4*)(src + base + 4);
    ushort4 d0, d1;
    d0.x = f2bf(a.x); d0.y = f2bf(a.y); d0.z = f2bf(a.z); d0.w = f2bf(a.w);
    d1.x = f2bf(b.x); d1.y = f2bf(b.y); d1.z = f2bf(b.z); d1.w = f2bf(b.w);
    *(ushort4*)(dst + base) = d0;
    *(ushort4*)(dst + base + 4) = d1;
  }
}

// Build split-bf16 weights: Wt2[layer][n][0..127]=Whi, [128..255]=Whi, [256..383]=Wlo
__global__ void build_wt(const float* __restrict__ W, u16* __restrict__ Wt2) {
  int idx = blockIdx.x * 256 + threadIdx.x;
  if (idx >= 4 * 128 * 128) return;
  int layer = idx >> 14;
  int n = (idx >> 7) & 127;
  int k = idx & 127;
  float e = W[idx];
  u16 hi = f2bf(e);
  u16 lo = f2bf(e - bf2f(hi));
  u16* base = Wt2 + (size_t)layer * 128 * 384 + (size_t)n * 384;
  base[k] = hi;
  base[128 + k] = hi;
  base[256 + k] = lo;
}

// write row i of split-bf16 activations A' = [hi, lo, hi]
__device__ __forceinline__ void write_split(u16* hs, int i, int lane, float v0, float v1) {
  u16* row = hs + (size_t)i * 384;
  u16 h0 = f2bf(v0), h1 = f2bf(v1);
  u16 l0 = f2bf(v0 - bf2f(h0)), l1 = f2bf(v1 - bf2f(h1));
  row[lane] = h0;         row[lane + 64] = h1;
  row[128 + lane] = l0;   row[128 + 64 + lane] = l1;
  row[256 + lane] = h0;   row[256 + 64 + lane] = h1;
}

// h = proj(expmap0(x)); res = h; hsplit = split(h). one wave per row.
__global__ __launch_bounds__(64) void rowwise_init(const float* __restrict__ x,
                                                   float* __restrict__ h,
                                                   float* __restrict__ res,
                                                   u16* __restrict__ hsplit) {
  int i = blockIdx.x, lane = threadIdx.x;
  const float* xr = x + (size_t)i * DD;
  float a0 = xr[lane], a1 = xr[lane + 64];
  float n = fmaxf(sqrtf(wave_sum(a0 * a0 + a1 * a1)), MIN_NORM);
  float g = tanhf(n) / n;
  float y0 = g * a0, y1 = g * a1;
  float pn = fmaxf(sqrtf(wave_sum(y0 * y0 + y1 * y1)), MIN_NORM);
  float s = pn > MAXN ? MAXN / pn : 1.0f;
  y0 *= s; y1 *= s;
  size_t base = (size_t)i * DD;
  h[base + lane] = y0;   h[base + lane + 64] = y1;
  res[base + lane] = y0; res[base + lane + 64] = y1;
  write_split(hsplit, i, lane, y0, y1);
}

// mobius_matvec tail + hyperbolic bias + mobius_add + logmap0 -> uT (bf16, n-major)
// mx comes in as 3 split-K partial buffers.
__global__ __launch_bounds__(64) void rowwise_mid(const float* __restrict__ h,
                                                  const float* __restrict__ P,
                                                  const float* __restrict__ bvec,
                                                  u16* __restrict__ uT) {
  int i = blockIdx.x, lane = threadIdx.x;
  size_t base = (size_t)i * DD;
  const float* hr = h + base;
  float h0 = hr[lane], h1 = hr[lane + 64];
  float m0 = 0.f, m1 = 0.f;
#pragma unroll
  for (int sk = 0; sk < 3; sk++) {
    const float* p = P + (size_t)sk * NN * DD + base;
    m0 += p[lane];
    m1 += p[lane + 64];
  }
  float xn = fmaxf(sqrtf(wave_sum(h0 * h0 + h1 * h1)), MIN_NORM);
  float mn = fmaxf(sqrtf(wave_sum(m0 * m0 + m1 * m1)), MIN_NORM);
  float t = tanhf(mn / xn * artanh_f(xn));
  float v0 = t * m0 / mn, v1 = t * m1 / mn;
  float pn = fmaxf(sqrtf(wave_sum(v0 * v0 + v1 * v1)), MIN_NORM);
  float sc = pn > MAXN ? MAXN / pn : 1.0f;
  v0 *= sc; v1 *= sc;
  // hyp_b = proj(expmap0(b))
  float b0 = bvec[lane], b1 = bvec[lane + 64];
  float bn = fmaxf(sqrtf(wave_sum(b0 * b0 + b1 * b1)), MIN_NORM);
  float gb = tanhf(bn) / bn;
  float e0 = gb * b0, e1 = gb * b1;
  float en = fmaxf(sqrtf(wave_sum(e0 * e0 + e1 * e1)), MIN_NORM);
  float sb = en > MAXN ? MAXN / en : 1.0f;
  e0 *= sb; e1 *= sb;
  // mobius_add(v, e)
  float x2 = wave_sum(v0 * v0 + v1 * v1);
  float y2 = wave_sum(e0 * e0 + e1 * e1);
  float xy = wave_sum(v0 * e0 + v1 * e1);
  float ca = 1.0f + 2.0f * xy + y2;
  float cb = 1.0f - x2;
  float den = fmaxf(1.0f + 2.0f * xy + x2 * y2, MIN_NORM);
  float t0 = (ca * v0 + cb * e0) / den, t1 = (ca * v1 + cb * e1) / den;
  float tn = fmaxf(sqrtf(wave_sum(t0 * t0 + t1 * t1)), MIN_NORM);
  float st = tn > MAXN ? MAXN / tn : 1.0f;
  t0 *= st; t1 *= st;
  // logmap0
  float pn2 = fmaxf(sqrtf(wave_sum(t0 * t0 + t1 * t1)), MIN_NORM);
  float gl = artanh_f(pn2) / pn2;
  uT[(size_t)lane * NN + i] = f2bf(gl * t0);
  uT[(size_t)(lane + 64) * NN + i] = f2bf(gl * t1);
}

// sum 8 split-K partials; proj(expmap0(m)); proj(expmap0(relu(logmap0(.))));
// optional euclidean residual add (and res update); write h + split.
__global__ __launch_bounds__(64) void rowwise_post(const float* __restrict__ P,
                                                   float* __restrict__ h,
                                                   float* __restrict__ res,
                                                   u16* __restrict__ hsplit,
                                                   int addres) {
  int i = blockIdx.x, lane = threadIdx.x;
  size_t base = (size_t)i * DD;
  float m0 = 0.f, m1 = 0.f;
#pragma unroll
  for (int sk = 0; sk < 8; sk++) {
    const float* p = P + (size_t)sk * NN * DD + base;
    m0 += p[lane];
    m1 += p[lane + 64];
  }
  float n = fmaxf(sqrtf(wave_sum(m0 * m0 + m1 * m1)), MIN_NORM);
  float g = tanhf(n) / n;
  float y0 = g * m0, y1 = g * m1;
  float pn = fmaxf(sqrtf(wave_sum(y0 * y0 + y1 * y1)), MIN_NORM);
  float s = pn > MAXN ? MAXN / pn : 1.0f;
  y0 *= s; y1 *= s;
  // act: relu in tangent space
  float hn = fmaxf(sqrtf(wave_sum(y0 * y0 + y1 * y1)), MIN_NORM);
  float gl = artanh_f(hn) / hn;
  float u0 = fmaxf(gl * y0, 0.0f), u1 = fmaxf(gl * y1, 0.0f);
  float un = fmaxf(sqrtf(wave_sum(u0 * u0 + u1 * u1)), MIN_NORM);
  float ge = tanhf(un) / un;
  float z0 = ge * u0, z1 = ge * u1;
  float zn = fmaxf(sqrtf(wave_sum(z0 * z0 + z1 * z1)), MIN_NORM);
  float sz = zn > MAXN ? MAXN / zn : 1.0f;
  z0 *= sz; z1 *= sz;
  if (addres) {
    z0 += res[base + lane];
    z1 += res[base + lane + 64];
    res[base + lane] = z0;
    res[base + lane + 64] = z1;
  }
  h[base + lane] = z0;
  h[base + lane + 64] = z1;
  write_split(hsplit, i, lane, z0, z1);
}

// pairwise poincare distance to 64 centroids, column-sum into rs[64]
__global__ __launch_bounds__(256) void centroid_k(const float* __restrict__ h,
                                                  const float* __restrict__ cen,
                                                  float* __restrict__ rs) {
  __shared__ float cs[64 * 129];
  __shared__ float hs[32 * 128];
  __shared__ float y2s[64];
  int tid = threadIdx.x;
  int i0 = blockIdx.x * 32;
  for (int idx = tid; idx < 64 * 128; idx += 256) {
    int r = idx >> 7, c = idx & 127;
    cs[r * 129 + c] = cen[idx];
  }
  for (int idx = tid; idx < 32 * 128; idx += 256) hs[idx] = h[(size_t)i0 * 128 + idx];
  __syncthreads();
  if (tid < 64) {
    float s = 0.f;
    for (int k = 0; k < 128; k++) { float v = cs[tid * 129 + k]; s = fmaf(v, v, s); }
    y2s[tid] = s;
  }
  __syncthreads();
  int w = tid >> 6, lane = tid & 63;
  float dsum = 0.f;
  for (int rr = 0; rr < 8; rr++) {
    int r = w * 8 + rr;
    float dot = 0.f, x2 = 0.f;
    for (int k = 0; k < 128; k++) {
      float hk = hs[r * 128 + k];
      dot = fmaf(hk, cs[lane * 129 + k], dot);
      x2 = fmaf(hk, hk, x2);
    }
    float y2 = y2s[lane];
    float al = 1.0f - 2.0f * dot + y2;   // coeff of (-x) in mobius_add(-x,y)
    float be = 1.0f - x2;
    float num2 = al * al * x2 + be * be * y2 - 2.0f * al * be * dot;
    float den = fmaxf(1.0f - 2.0f * dot + x2 * y2, MIN_NORM);
    float d = fmaxf(sqrtf(fmaxf(num2, 0.0f)) / den, MIN_NORM);
    dsum += 2.0f * artanh_f(d);
  }
  atomicAdd(&rs[lane], dsum);
}

// readout mean -> logmap0 -> h_r; logits (softmax over size-1 axis) = 1.0
__global__ __launch_bounds__(64) void finalize_k(const float* __restrict__ rs,
                                                 float* __restrict__ out) {
  int lane = threadIdx.x;
  float r = rs[lane] * (1.0f / 8192.0f);
  float n = fmaxf(sqrtf(wave_sum(r * r)), MIN_NORM);
  float a = artanh_f(n);
  out[7 + NN * 7 + lane] = a * r / n;
  if (lane < 7) out[lane] = 1.0f;
}

// per-node scores: logmap0(h) @ W_mlp1^T + b_mlp1
__global__ __launch_bounds__(64) void scores_k(const float* __restrict__ h,
                                               const float* __restrict__ Wm,
                                               const float* __restrict__ bm,
                                               float* __restrict__ sc) {
  int i = blockIdx.x, lane = threadIdx.x;
  const float* hr = h + (size_t)i * DD;
  float h0 = hr[lane], h1 = hr[lane + 64];
  float pn = fmaxf(sqrtf(wave_sum(h0 * h0 + h1 * h1)), MIN_NORM);
  float gl = artanh_f(pn) / pn;
  float u0 = gl * h0, u1 = gl * h1;
  float p[7];
#pragma unroll
  for (int j = 0; j < 7; j++)
    p[j] = wave_sum(u0 * Wm[j * 128 + lane] + u1 * Wm[j * 128 + lane + 64]);
  float v = p[0];
#pragma unroll
  for (int j = 1; j < 7; j++)
    if (lane == j) v = p[j];
  if (lane < 7) sc[(size_t)i * 7 + lane] = v + bm[lane];
}

// softmax over axis 0 (8192 nodes) per class column
__global__ __launch_bounds__(256) void softmax_col(const float* __restrict__ sc,
                                                   float* __restrict__ out) {
  __shared__ float buf[256][8];
  int tid = threadIdx.x;
  float mx[7];
#pragma unroll
  for (int j = 0; j < 7; j++) mx[j] = -1e30f;
  for (int i = tid; i < NN; i += 256)
#pragma unroll
    for (int j = 0; j < 7; j++) mx[j] = fmaxf(mx[j], sc[i * 7 + j]);
#pragma unroll
  for (int j = 0; j < 7; j++) buf[tid][j] = mx[j];
  __syncthreads();
  for (int off = 128; off > 0; off >>= 1) {
    if (tid < off)
#pragma unroll
      for (int j = 0; j < 7; j++) buf[tid][j] = fmaxf(buf[tid][j], buf[tid + off][j]);
    __syncthreads();
  }
  float cm[7];
#pragma unroll
  for (int j = 0; j < 7; j++) cm[j] = buf[0][j];
  __syncthreads();
  float sm[7];
#pragma unroll
  for (int j = 0; j < 7; j++) sm[j] = 0.f;
  for (int i = tid; i < NN; i += 256)
#pragma unroll
    for (int j = 0; j < 7; j++) sm[j] += expf(sc[i * 7 + j] - cm[j]);
#pragma unroll
  for (int j = 0; j < 7; j++) buf[tid][j] = sm[j];
  __syncthreads();
  for (int off = 128; off > 0; off >>= 1) {
    if (tid < off)
#pragma unroll
      for (int j = 0; j < 7; j++) buf[tid][j] += buf[tid + off][j];
    __syncthreads();
  }
  float csum[7];
#pragma unroll
  for (int j = 0; j < 7; j++) csum[j] = buf[0][j];
  __syncthreads();
  for (int idx = tid; idx < NN * 7; idx += 256) {
    int i = idx / 7, j = idx - i * 7;
    out[idx] = expf(sc[i * 7 + j] - cm[j]) / csum[j];
  }
}

extern "C" void kernel_launch(void* const* d_in, const int* in_sizes, int n_in,
                              void* d_out, int out_size, void* d_ws, size_t ws_size,
                              hipStream_t stream) {
  const float* x = (const float*)d_in[0];
  const float* adj = (const float*)d_in[1];
  const float* W_conv = (const float*)d_in[3];
  const float* b_conv = (const float*)d_in[4];
  const float* centroids = (const float*)d_in[5];
  const float* W_mlp1 = (const float*)d_in[8];
  const float* b_mlp1 = (const float*)d_in[9];
  float* out = (float*)d_out;

  char* ws = (char*)d_ws;
  size_t off = 0;
  auto alloc = [&](size_t bytes) {
    void* p = ws + off;
    off = (off + bytes + 255) & ~(size_t)255;
    return p;
  };
  float* h = (float*)alloc((size_t)NN * DD * 4);
  float* res = (float*)alloc((size_t)NN * DD * 4);
  u16* hsplit = (u16*)alloc((size_t)NN * 384 * 2);
  u16* uT = (u16*)alloc((size_t)DD * NN * 2);
  u16* Wt2 = (u16*)alloc((size_t)4 * 128 * 384 * 2);
  float* P = (float*)alloc((size_t)8 * NN * DD * 4);
  u16* adjbf = (u16*)alloc((size_t)NN * NN * 2);
  float* scores = (float*)alloc((size_t)NN * 7 * 4);
  float* rs = (float*)alloc(64 * 4);
  (void)ws_size; (void)in_sizes; (void)n_in; (void)out_size;

  hipMemsetAsync(rs, 0, 64 * 4, stream);
  build_wt<<<(4 * 128 * 128 + 255) / 256, 256, 0, stream>>>(W_conv, Wt2);
  rowwise_init<<<NN, 64, 0, stream>>>(x, h, res, hsplit);
  cvt_adj<<<2048, 256, 0, stream>>>(adj, adjbf);
  for (int layer = 0; layer < 4; layer++) {
    // HypLinear matvec: mx = h @ W^T via split-bf16 (K=384), split-K=3
    gemm_bt<<<dim3(NN / 64, 3), 256, 0, stream>>>(
        hsplit, Wt2 + (size_t)layer * 128 * 384, P, NN, 384, 128);
    rowwise_mid<<<NN, 64, 0, stream>>>(h, P, b_conv + layer * DD, uT);
    // HypAgg: m = adj @ u, split-K=8 partials (all-bf16 adj)
    gemm_bt<<<dim3(NN / 64, 8), 256, 0, stream>>>(
        adjbf, uT, P, NN, NN, NN / 8);
    rowwise_post<<<NN, 64, 0, stream>>>(P, h, res, hsplit, (layer & 1));
  }
  centroid_k<<<256, 256, 0, stream>>>(h, centroids, rs);
  finalize_k<<<1, 64, 0, stream>>>(rs, out);
  scores_k<<<NN, 64, 0, stream>>>(h, W_mlp1, b_mlp1, scores);
  softmax_col<<<1, 256, 0, stream>>>(scores, out + 7);
}

// Round 6
// 811.944 us; speedup vs baseline: 1.0066x; 1.0066x over previous
//
#include <hip/hip_runtime.h>

#define MIN_NORM 1e-15f
#define EPSV 1e-5f
#define MAXN (1.0f - EPSV)
#define NN 8192
#define DD 128

typedef unsigned short u16;
typedef __bf16 bf16x8 __attribute__((ext_vector_type(8)));
typedef float f32x4 __attribute__((ext_vector_type(4)));

__device__ __forceinline__ float wave_sum(float v) {
#pragma unroll
  for (int off = 32; off > 0; off >>= 1) v += __shfl_xor(v, off, 64);
  return v;
}

__device__ __forceinline__ float artanh_f(float x) {
  x = fminf(fmaxf(x, -1.0f + EPSV), 1.0f - EPSV);
  return 0.5f * (log1pf(x) - log1pf(-x));
}

// manual fp32 -> bf16 (RNE) and back
__device__ __forceinline__ u16 f2bf(float f) {
  unsigned u = __float_as_uint(f);
  unsigned r = (u + 0x7fffu + ((u >> 16) & 1u)) >> 16;
  return (u16)r;
}
__device__ __forceinline__ float bf2f(u16 b) { return __uint_as_float(((unsigned)b) << 16); }

// async global->LDS DMA, 16 B per lane. LDS dest = wave-uniform base + lane*16.
__device__ __forceinline__ void gload16(const u16* g, u16* l) {
  __builtin_amdgcn_global_load_lds((const __attribute__((address_space(1))) void*)(g),
                                   (__attribute__((address_space(3))) void*)(l), 16, 0, 0);
}

// ---------------------------------------------------------------------------
// GEMM: C[M][128] = A[M][K] * B[128][K]^T, bf16 inputs, fp32 split-K partials.
// BM=64, BN=128, BK=64; 256 threads = 4 waves (2x2), wave tile 32x64.
// global_load_lds staging, double-buffered LDS, one barrier per K-tile.
//
// TILED=true (adj path): A and B are PRE-TILED + PRE-SWIZZLED by their
// producers: A tile (xblk,kt) = 4096 u16 contiguous, layout [64 rows][8
// chunks] with physical chunk = logical ^ (row&7); B tile (kt) = 8192 u16
// [128 n][8 chunks] same swizzle. Every gload16 then reads base + lane*16B
// -- perfectly LINEAR 1-KB bursts (fill-shaped streams). Rationale: rounds
// 1-5 all measured ~1.8 TB/s on strided-island reads (128-256 B at 32-KB
// row stride) while linear fills hit 6.7 TB/s on the same chip -> the
// access pattern, not overlap, is the bottleneck.
//
// TILED=false (weight path, small): row-major A/B with the XOR applied on
// the per-lane GLOBAL source chunk (round-5 scheme).
// Both paths share the compute: ds_read applies chunk^(row&7) -> the
// 16-rows-same-column b128 read spreads over all 8 bank-quads.
// ---------------------------------------------------------------------------
template <bool TILED>
__global__ __launch_bounds__(256) void gemm_bt(const u16* __restrict__ A,
                                               const u16* __restrict__ Bt,
                                               float* __restrict__ Cp,
                                               int M, int K, int KC) {
  __shared__ __align__(16) u16 Ash[2 * 64 * 64];    // 16 KB (2 bufs)
  __shared__ __align__(16) u16 Bsh[2 * 128 * 64];   // 32 KB (2 bufs)

  const int tid = threadIdx.x;
  const int lane = tid & 63;
  const int w = tid >> 6;
  const int wm = w >> 1, wn = w & 1;
  const int lrow = lane & 15;
  const int lq = lane >> 4;
  const int m0 = blockIdx.x * 64;
  const int kk0 = blockIdx.y * KC;
  const int kt0 = kk0 >> 6;
  const int bxK = blockIdx.x * (K >> 6);

  const int srow = lane >> 3;   // non-tiled staging: sub-row within 8-row group
  const int spc = lane & 7;     // non-tiled staging: physical chunk this lane fills

  const u16* Ap = A + (TILED ? 0 : (size_t)m0 * K);

  f32x4 acc[2][4];
#pragma unroll
  for (int a = 0; a < 2; a++)
#pragma unroll
    for (int b = 0; b < 4; b++)
#pragma unroll
      for (int r = 0; r < 4; r++) acc[a][b][r] = 0.0f;

#define STAGE(bf, tkt, kk)                                                     \
  do {                                                                         \
    if constexpr (TILED) {                                                     \
      const u16* at = A + (((size_t)(bxK + (tkt))) << 12) + (lane << 3);       \
      _Pragma("unroll") for (int ii = 0; ii < 2; ii++)                         \
        gload16(at + ((ii * 4 + w) << 9), &Ash[(bf) * 4096 + ((ii * 4 + w) << 9)]); \
      const u16* bt2 = Bt + (((size_t)(tkt)) << 13) + (lane << 3);             \
      _Pragma("unroll") for (int ii = 0; ii < 4; ii++)                         \
        gload16(bt2 + ((ii * 4 + w) << 9), &Bsh[(bf) * 8192 + ((ii * 4 + w) << 9)]); \
    } else {                                                                   \
      _Pragma("unroll") for (int ii = 0; ii < 2; ii++) {                       \
        int rw = ((ii * 4 + w) << 3) + srow;                                   \
        gload16(Ap + (size_t)rw * K + (kk) + ((spc ^ (rw & 7)) << 3),          \
                &Ash[(bf) * 4096 + ((ii * 4 + w) << 9)]);                      \
      }                                                                        \
      _Pragma("unroll") for (int ii = 0; ii < 4; ii++) {                       \
        int rw = ((ii * 4 + w) << 3) + srow;                                   \
        gload16(Bt + (size_t)rw * K + (kk) + ((spc ^ (rw & 7)) << 3),          \
                &Bsh[(bf) * 8192 + ((ii * 4 + w) << 9)]);                      \
      }                                                                        \
    }                                                                          \
  } while (0)

  const int nt = KC >> 6;
  STAGE(0, kt0, kk0);  // prologue

  for (int t = 0; t < nt; t++) {
    const int cur = t & 1;
    __syncthreads();  // vmcnt(0) drain: buf[cur] ready; buf[cur^1] reusable
    if (t + 1 < nt) STAGE(cur ^ 1, kt0 + t + 1, kk0 + (t + 1) * 64);

    const int abase = cur * 4096, bbase = cur * 8192;
#pragma unroll
    for (int ks = 0; ks < 2; ks++) {
      const int lc = ks * 4 + lq;  // logical 16-B chunk within row
      bf16x8 af[2], bfr[4];
#pragma unroll
      for (int ti = 0; ti < 2; ti++) {
        int r = wm * 32 + ti * 16 + lrow;
        af[ti] = *(const bf16x8*)&Ash[abase + r * 64 + ((lc ^ (r & 7)) << 3)];
      }
#pragma unroll
      for (int tj = 0; tj < 4; tj++) {
        int n = wn * 64 + tj * 16 + lrow;
        bfr[tj] = *(const bf16x8*)&Bsh[bbase + n * 64 + ((lc ^ (n & 7)) << 3)];
      }
#pragma unroll
      for (int ti = 0; ti < 2; ti++)
#pragma unroll
        for (int tj = 0; tj < 4; tj++)
          acc[ti][tj] = __builtin_amdgcn_mfma_f32_16x16x32_bf16(af[ti], bfr[tj], acc[ti][tj], 0, 0, 0);
    }
  }
#undef STAGE

  float* C = Cp + (size_t)blockIdx.y * M * 128;
#pragma unroll
  for (int ti = 0; ti < 2; ti++)
#pragma unroll
    for (int tj = 0; tj < 4; tj++)
#pragma unroll
      for (int r = 0; r < 4; r++) {
        int row = m0 + wm * 32 + ti * 16 + lq * 4 + r;
        int col = wn * 64 + tj * 16 + lrow;
        C[(size_t)row * 128 + col] = acc[ti][tj][r];
      }
}

// fp32 adj -> tiled+swizzled bf16 adjT. Block (xb, kg): rows xb*64..+64,
// k = kg*512..+512. Reads 2-KB contiguous runs per row; writes 8-KB tiles.
__global__ __launch_bounds__(256) void cvt_tile(const float* __restrict__ src,
                                                u16* __restrict__ dst) {
  int tid = threadIdx.x;
  int xb = blockIdx.x;          // 0..127 row-panel
  int kg = blockIdx.y;          // 0..15
  int ch = tid & 63;            // 8-fp32 chunk within the 512-k group
  int rs = tid >> 6;            // 0..3
#pragma unroll
  for (int rr = 0; rr < 16; rr++) {
    int row = rr * 4 + rs;
    int gk = kg * 512 + ch * 8;
    const float* s = src + (size_t)(xb * 64 + row) * NN + gk;
    float4 a = *(const float4*)s;
    float4 b = *(const float4*)(s + 4);
    ushort4 d0, d1;
    d0.x = f2bf(a.x); d0.y = f2bf(a.y); d0.z = f2bf(a.z); d0.w = f2bf(a.w);
    d1.x = f2bf(b.x); d1.y = f2bf(b.y); d1.z = f2bf(b.z); d1.w = f2bf(b.w);
    u16* d = dst + (((size_t)(xb * 128 + (gk >> 6))) << 12) + row * 64 +
             ((((gk >> 3) & 7) ^ (row & 7)) << 3);
    *(ushort4*)d = d0;
    *(ushort4*)(d + 4) = d1;
  }
}

// Build split-bf16 weights: Wt2[layer][n][0..127]=Whi, [128..255]=Whi, [256..383]=Wlo
__global__ void build_wt(const float* __restrict__ W, u16* __restrict__ Wt2) {
  int idx = blockIdx.x * 256 + threadIdx.x;
  if (idx >= 4 * 128 * 128) return;
  int layer = idx >> 14;
  int n = (idx >> 7) & 127;
  int k = idx & 127;
  float e = W[idx];
  u16 hi = f2bf(e);
  u16 lo = f2bf(e - bf2f(hi));
  u16* base = Wt2 + (size_t)layer * 128 * 384 + (size_t)n * 384;
  base[k] = hi;
  base[128 + k] = hi;
  base[256 + k] = lo;
}

// write row i of split-bf16 activations A' = [hi, lo, hi]
__device__ __forceinline__ void write_split(u16* hs, int i, int lane, float v0, float v1) {
  u16* row = hs + (size_t)i * 384;
  u16 h0 = f2bf(v0), h1 = f2bf(v1);
  u16 l0 = f2bf(v0 - bf2f(h0)), l1 = f2bf(v1 - bf2f(h1));
  row[lane] = h0;         row[lane + 64] = h1;
  row[128 + lane] = l0;   row[128 + 64 + lane] = l1;
  row[256 + lane] = h0;   row[256 + 64 + lane] = h1;
}

// h = proj(expmap0(x)); res = h; hsplit = split(h). one wave per row.
__global__ __launch_bounds__(64) void rowwise_init(const float* __restrict__ x,
                                                   float* __restrict__ h,
                                                   float* __restrict__ res,
                                                   u16* __restrict__ hsplit) {
  int i = blockIdx.x, lane = threadIdx.x;
  const float* xr = x + (size_t)i * DD;
  float a0 = xr[lane], a1 = xr[lane + 64];
  float n = fmaxf(sqrtf(wave_sum(a0 * a0 + a1 * a1)), MIN_NORM);
  float g = tanhf(n) / n;
  float y0 = g * a0, y1 = g * a1;
  float pn = fmaxf(sqrtf(wave_sum(y0 * y0 + y1 * y1)), MIN_NORM);
  float s = pn > MAXN ? MAXN / pn : 1.0f;
  y0 *= s; y1 *= s;
  size_t base = (size_t)i * DD;
  h[base + lane] = y0;   h[base + lane + 64] = y1;
  res[base + lane] = y0; res[base + lane + 64] = y1;
  write_split(hsplit, i, lane, y0, y1);
}

// mobius_matvec tail + hyperbolic bias + mobius_add + logmap0 -> uT2
// (tiled+swizzled bf16 layout matching gemm_bt<true>'s B staging).
__global__ __launch_bounds__(64) void rowwise_mid(const float* __restrict__ h,
                                                  const float* __restrict__ P,
                                                  const float* __restrict__ bvec,
                                                  u16* __restrict__ uT2) {
  int i = blockIdx.x, lane = threadIdx.x;
  size_t base = (size_t)i * DD;
  const float* hr = h + base;
  float h0 = hr[lane], h1 = hr[lane + 64];
  float m0 = 0.f, m1 = 0.f;
#pragma unroll
  for (int sk = 0; sk < 3; sk++) {
    const float* p = P + (size_t)sk * NN * DD + base;
    m0 += p[lane];
    m1 += p[lane + 64];
  }
  float xn = fmaxf(sqrtf(wave_sum(h0 * h0 + h1 * h1)), MIN_NORM);
  float mn = fmaxf(sqrtf(wave_sum(m0 * m0 + m1 * m1)), MIN_NORM);
  float t = tanhf(mn / xn * artanh_f(xn));
  float v0 = t * m0 / mn, v1 = t * m1 / mn;
  float pn = fmaxf(sqrtf(wave_sum(v0 * v0 + v1 * v1)), MIN_NORM);
  float sc = pn > MAXN ? MAXN / pn : 1.0f;
  v0 *= sc; v1 *= sc;
  // hyp_b = proj(expmap0(b))
  float b0 = bvec[lane], b1 = bvec[lane + 64];
  float bn = fmaxf(sqrtf(wave_sum(b0 * b0 + b1 * b1)), MIN_NORM);
  float gb = tanhf(bn) / bn;
  float e0 = gb * b0, e1 = gb * b1;
  float en = fmaxf(sqrtf(wave_sum(e0 * e0 + e1 * e1)), MIN_NORM);
  float sb = en > MAXN ? MAXN / en : 1.0f;
  e0 *= sb; e1 *= sb;
  // mobius_add(v, e)
  float x2 = wave_sum(v0 * v0 + v1 * v1);
  float y2 = wave_sum(e0 * e0 + e1 * e1);
  float xy = wave_sum(v0 * e0 + v1 * e1);
  float ca = 1.0f + 2.0f * xy + y2;
  float cb = 1.0f - x2;
  float den = fmaxf(1.0f + 2.0f * xy + x2 * y2, MIN_NORM);
  float t0 = (ca * v0 + cb * e0) / den, t1 = (ca * v1 + cb * e1) / den;
  float tn = fmaxf(sqrtf(wave_sum(t0 * t0 + t1 * t1)), MIN_NORM);
  float st = tn > MAXN ? MAXN / tn : 1.0f;
  t0 *= st; t1 *= st;
  // logmap0
  float pn2 = fmaxf(sqrtf(wave_sum(t0 * t0 + t1 * t1)), MIN_NORM);
  float gl = artanh_f(pn2) / pn2;
  // tiled+swizzled store: element (n, k=i) -> tile i>>6, offset
  // n*64 + ((chunk ^ (n&7))<<3) + (i&7), chunk = (i>>3)&7
  u16* tb = uT2 + (((size_t)(i >> 6)) << 13);
  int c8 = (i >> 3) & 7, k7 = i & 7;
  tb[lane * 64 + (((c8) ^ (lane & 7)) << 3) + k7] = f2bf(gl * t0);
  int n2 = lane + 64;
  tb[n2 * 64 + (((c8) ^ (n2 & 7)) << 3) + k7] = f2bf(gl * t1);
}

// sum 8 split-K partials; proj(expmap0(m)); proj(expmap0(relu(logmap0(.))));
// optional euclidean residual add (and res update); write h + split.
__global__ __launch_bounds__(64) void rowwise_post(const float* __restrict__ P,
                                                   float* __restrict__ h,
                                                   float* __restrict__ res,
                                                   u16* __restrict__ hsplit,
                                                   int addres) {
  int i = blockIdx.x, lane = threadIdx.x;
  size_t base = (size_t)i * DD;
  float m0 = 0.f, m1 = 0.f;
#pragma unroll
  for (int sk = 0; sk < 8; sk++) {
    const float* p = P + (size_t)sk * NN * DD + base;
    m0 += p[lane];
    m1 += p[lane + 64];
  }
  float n = fmaxf(sqrtf(wave_sum(m0 * m0 + m1 * m1)), MIN_NORM);
  float g = tanhf(n) / n;
  float y0 = g * m0, y1 = g * m1;
  float pn = fmaxf(sqrtf(wave_sum(y0 * y0 + y1 * y1)), MIN_NORM);
  float s = pn > MAXN ? MAXN / pn : 1.0f;
  y0 *= s; y1 *= s;
  // act: relu in tangent space
  float hn = fmaxf(sqrtf(wave_sum(y0 * y0 + y1 * y1)), MIN_NORM);
  float gl = artanh_f(hn) / hn;
  float u0 = fmaxf(gl * y0, 0.0f), u1 = fmaxf(gl * y1, 0.0f);
  float un = fmaxf(sqrtf(wave_sum(u0 * u0 + u1 * u1)), MIN_NORM);
  float ge = tanhf(un) / un;
  float z0 = ge * u0, z1 = ge * u1;
  float zn = fmaxf(sqrtf(wave_sum(z0 * z0 + z1 * z1)), MIN_NORM);
  float sz = zn > MAXN ? MAXN / zn : 1.0f;
  z0 *= sz; z1 *= sz;
  if (addres) {
    z0 += res[base + lane];
    z1 += res[base + lane + 64];
    res[base + lane] = z0;
    res[base + lane + 64] = z1;
  }
  h[base + lane] = z0;
  h[base + lane + 64] = z1;
  write_split(hsplit, i, lane, z0, z1);
}

// pairwise poincare distance to 64 centroids, column-sum into rs[64]
__global__ __launch_bounds__(256) void centroid_k(const float* __restrict__ h,
                                                  const float* __restrict__ cen,
                                                  float* __restrict__ rs) {
  __shared__ float cs[64 * 129];
  __shared__ float hs[32 * 128];
  __shared__ float y2s[64];
  int tid = threadIdx.x;
  int i0 = blockIdx.x * 32;
  for (int idx = tid; idx < 64 * 128; idx += 256) {
    int r = idx >> 7, c = idx & 127;
    cs[r * 129 + c] = cen[idx];
  }
  for (int idx = tid; idx < 32 * 128; idx += 256) hs[idx] = h[(size_t)i0 * 128 + idx];
  __syncthreads();
  if (tid < 64) {
    float s = 0.f;
    for (int k = 0; k < 128; k++) { float v = cs[tid * 129 + k]; s = fmaf(v, v, s); }
    y2s[tid] = s;
  }
  __syncthreads();
  int w = tid >> 6, lane = tid & 63;
  float dsum = 0.f;
  for (int rr = 0; rr < 8; rr++) {
    int r = w * 8 + rr;
    float dot = 0.f, x2 = 0.f;
    for (int k = 0; k < 128; k++) {
      float hk = hs[r * 128 + k];
      dot = fmaf(hk, cs[lane * 129 + k], dot);
      x2 = fmaf(hk, hk, x2);
    }
    float y2 = y2s[lane];
    float al = 1.0f - 2.0f * dot + y2;   // coeff of (-x) in mobius_add(-x,y)
    float be = 1.0f - x2;
    float num2 = al * al * x2 + be * be * y2 - 2.0f * al * be * dot;
    float den = fmaxf(1.0f - 2.0f * dot + x2 * y2, MIN_NORM);
    float d = fmaxf(sqrtf(fmaxf(num2, 0.0f)) / den, MIN_NORM);
    dsum += 2.0f * artanh_f(d);
  }
  atomicAdd(&rs[lane], dsum);
}

// readout mean -> logmap0 -> h_r; logits (softmax over size-1 axis) = 1.0
__global__ __launch_bounds__(64) void finalize_k(const float* __restrict__ rs,
                                                 float* __restrict__ out) {
  int lane = threadIdx.x;
  float r = rs[lane] * (1.0f / 8192.0f);
  float n = fmaxf(sqrtf(wave_sum(r * r)), MIN_NORM);
  float a = artanh_f(n);
  out[7 + NN * 7 + lane] = a * r / n;
  if (lane < 7) out[lane] = 1.0f;
}

// per-node scores: logmap0(h) @ W_mlp1^T + b_mlp1
__global__ __launch_bounds__(64) void scores_k(const float* __restrict__ h,
                                               const float* __restrict__ Wm,
                                               const float* __restrict__ bm,
                                               float* __restrict__ sc) {
  int i = blockIdx.x, lane = threadIdx.x;
  const float* hr = h + (size_t)i * DD;
  float h0 = hr[lane], h1 = hr[lane + 64];
  float pn = fmaxf(sqrtf(wave_sum(h0 * h0 + h1 * h1)), MIN_NORM);
  float gl = artanh_f(pn) / pn;
  float u0 = gl * h0, u1 = gl * h1;
  float p[7];
#pragma unroll
  for (int j = 0; j < 7; j++)
    p[j] = wave_sum(u0 * Wm[j * 128 + lane] + u1 * Wm[j * 128 + lane + 64]);
  float v = p[0];
#pragma unroll
  for (int j = 1; j < 7; j++)
    if (lane == j) v = p[j];
  if (lane < 7) sc[(size_t)i * 7 + lane] = v + bm[lane];
}

// softmax over axis 0 (8192 nodes) per class column
__global__ __launch_bounds__(256) void softmax_col(const float* __restrict__ sc,
                                                   float* __restrict__ out) {
  __shared__ float buf[256][8];
  int tid = threadIdx.x;
  float mx[7];
#pragma unroll
  for (int j = 0; j < 7; j++) mx[j] = -1e30f;
  for (int i = tid; i < NN; i += 256)
#pragma unroll
    for (int j = 0; j < 7; j++) mx[j] = fmaxf(mx[j], sc[i * 7 + j]);
#pragma unroll
  for (int j = 0; j < 7; j++) buf[tid][j] = mx[j];
  __syncthreads();
  for (int off = 128; off > 0; off >>= 1) {
    if (tid < off)
#pragma unroll
      for (int j = 0; j < 7; j++) buf[tid][j] = fmaxf(buf[tid][j], buf[tid + off][j]);
    __syncthreads();
  }
  float cm[7];
#pragma unroll
  for (int j = 0; j < 7; j++) cm[j] = buf[0][j];
  __syncthreads();
  float sm[7];
#pragma unroll
  for (int j = 0; j < 7; j++) sm[j] = 0.f;
  for (int i = tid; i < NN; i += 256)
#pragma unroll
    for (int j = 0; j < 7; j++) sm[j] += expf(sc[i * 7 + j] - cm[j]);
#pragma unroll
  for (int j = 0; j < 7; j++) buf[tid][j] = sm[j];
  __syncthreads();
  for (int off = 128; off > 0; off >>= 1) {
    if (tid < off)
#pragma unroll
      for (int j = 0; j < 7; j++) buf[tid][j] += buf[tid + off][j];
    __syncthreads();
  }
  float csum[7];
#pragma unroll
  for (int j = 0; j < 7; j++) csum[j] = buf[0][j];
  __syncthreads();
  for (int idx = tid; idx < NN * 7; idx += 256) {
    int i = idx / 7, j = idx - i * 7;
    out[idx] = expf(sc[i * 7 + j] - cm[j]) / csum[j];
  }
}

extern "C" void kernel_launch(void* const* d_in, const int* in_sizes, int n_in,
                              void* d_out, int out_size, void* d_ws, size_t ws_size,
                              hipStream_t stream) {
  const float* x = (const float*)d_in[0];
  const float* adj = (const float*)d_in[1];
  const float* W_conv = (const float*)d_in[3];
  const float* b_conv = (const float*)d_in[4];
  const float* centroids = (const float*)d_in[5];
  const float* W_mlp1 = (const float*)d_in[8];
  const float* b_mlp1 = (const float*)d_in[9];
  float* out = (float*)d_out;

  char* ws = (char*)d_ws;
  size_t off = 0;
  auto alloc = [&](size_t bytes) {
    void* p = ws + off;
    off = (off + bytes + 255) & ~(size_t)255;
    return p;
  };
  float* h = (float*)alloc((size_t)NN * DD * 4);
  float* res = (float*)alloc((size_t)NN * DD * 4);
  u16* hsplit = (u16*)alloc((size_t)NN * 384 * 2);
  u16* uT2 = (u16*)alloc((size_t)DD * NN * 2);
  u16* Wt2 = (u16*)alloc((size_t)4 * 128 * 384 * 2);
  float* P = (float*)alloc((size_t)8 * NN * DD * 4);
  u16* adjT = (u16*)alloc((size_t)NN * NN * 2);
  float* scores = (float*)alloc((size_t)NN * 7 * 4);
  float* rs = (float*)alloc(64 * 4);
  (void)ws_size; (void)in_sizes; (void)n_in; (void)out_size;

  hipMemsetAsync(rs, 0, 64 * 4, stream);
  build_wt<<<(4 * 128 * 128 + 255) / 256, 256, 0, stream>>>(W_conv, Wt2);
  rowwise_init<<<NN, 64, 0, stream>>>(x, h, res, hsplit);
  cvt_tile<<<dim3(128, 16), 256, 0, stream>>>(adj, adjT);
  for (int layer = 0; layer < 4; layer++) {
    // HypLinear matvec: mx = h @ W^T via split-bf16 (K=384), split-K=3
    gemm_bt<false><<<dim3(NN / 64, 3), 256, 0, stream>>>(
        hsplit, Wt2 + (size_t)layer * 128 * 384, P, NN, 384, 128);
    rowwise_mid<<<NN, 64, 0, stream>>>(h, P, b_conv + layer * DD, uT2);
    // HypAgg: m = adj @ u, split-K=8 partials, tiled+swizzled operands
    gemm_bt<true><<<dim3(NN / 64, 8), 256, 0, stream>>>(
        adjT, uT2, P, NN, NN, NN / 8);
    rowwise_post<<<NN, 64, 0, stream>>>(P, h, res, hsplit, (layer & 1));
  }
  centroid_k<<<256, 256, 0, stream>>>(h, centroids, rs);
  finalize_k<<<1, 64, 0, stream>>>(rs, out);
  scores_k<<<NN, 64, 0, stream>>>(h, W_mlp1, b_mlp1, scores);
  softmax_col<<<1, 256, 0, stream>>>(scores, out + 7);
}